// Round 15
// baseline (141.354 us; speedup 1.0000x reference)
//
#include <hip/hip_runtime.h>
#include <math.h>

namespace {

constexpr int HW  = 196;
constexpr int HWP = 224;
constexpr int OC  = 2048;
constexpr float TEMP   = 0.35355339059327373f;  // 1/sqrt(KEY_DIM)
constexpr float INV196 = 1.0f / 196.0f;

typedef __attribute__((ext_vector_type(8))) _Float16 half8;
typedef __attribute__((ext_vector_type(4))) float f32x4;

__device__ __forceinline__ void gload_lds16(const void* g, void* l) {
  __builtin_amdgcn_global_load_lds(
      (const __attribute__((address_space(1))) void*)g,
      (__attribute__((address_space(3))) void*)l, 16, 0, 0);
}

#define MFMAH(a, b, c) __builtin_amdgcn_mfma_f32_16x16x32_f16((a), (b), (c), 0, 0, 0)

// ================= K1: WvA prep (512 blocks) || pool (4096 blocks, XCD-affine) =================
__global__ __launch_bounds__(256) void fat_prep(
    const float* __restrict__ x, const float* __restrict__ Wv,
    _Float16* __restrict__ WvA,
    _Float16* __restrict__ xpH, float* __restrict__ xm) {
  __shared__ float tl[8][264];
  int bid = blockIdx.x;
  int t = threadIdx.x;
  if (bid < 512) {
    // ---- WvA f16 hi/lo fragments ----
    int kk = bid >> 5;
    int rq = bid & 31;
    int w = t >> 6, lane = t & 63;
    int r = rq * 4 + w;
    int oc = r * 16 + (lane & 15);
    int c0 = kk * 32 + (lane >> 4) * 8;
    const float* src = Wv + (size_t)oc * 512 + c0;
    float4 v0 = *(const float4*)src;
    float4 v1 = *(const float4*)(src + 4);
    float vals[8] = {v0.x, v0.y, v0.z, v0.w, v1.x, v1.y, v1.z, v1.w};
    half8 hi, lo;
    #pragma unroll
    for (int e = 0; e < 8; ++e) {
      _Float16 h = (_Float16)vals[e];
      hi[e] = h;
      lo[e] = (_Float16)(vals[e] - (float)h);
    }
    *(half8*)(WvA + ((size_t)(kk * 2 + 0) * 128 + r) * 512 + lane * 8) = hi;
    *(half8*)(WvA + ((size_t)(kk * 2 + 1) * 128 + r) * 512 + lane * 8) = lo;
  } else {
    // ---- pool: avgpool3x3 + spatial mean -> f16 xp hi only, [nd][hw][c] ----
    int pb = bid - 512;
    int nd = (((pb >> 9) & 7) << 3) | (pb & 7);   // XCD-affine
    int cg = (pb >> 3) & 63;
    int n = nd >> 5, d = nd & 31;
    int c0 = cg * 8;
    int cl = t >> 5, s = t & 31;
    const float* xr = x + (((size_t)(n * 512 + c0 + cl)) * 32 + d) * 256;
    float4 va = *(const float4*)(xr + s * 8);
    float4 vb = *(const float4*)(xr + s * 8 + 4);
    *(float4*)&tl[cl][s * 8] = va;
    *(float4*)&tl[cl][s * 8 + 4] = vb;
    float rs = va.x + va.y + va.z + va.w + vb.x + vb.y + vb.z + vb.w;
    #pragma unroll
    for (int off = 16; off; off >>= 1) rs += __shfl_xor(rs, off, 32);
    if (s == 0) xm[nd * 512 + c0 + cl] = rs * (1.0f / 256.0f);
    __syncthreads();
    if (t < HWP) {
      int hw = t;
      half8 hi;
      if (hw < HW) {
        int y = hw / 14, xx = hw - y * 14;
        #pragma unroll
        for (int c = 0; c < 8; ++c) {
          const float* q = &tl[c][y * 16 + xx];
          float val = (q[0] + q[1] + q[2] + q[16] + q[17] + q[18] +
                       q[32] + q[33] + q[34]) * (1.0f / 9.0f);
          hi[c] = (_Float16)val;
        }
      } else {
        #pragma unroll
        for (int c = 0; c < 8; ++c) hi[c] = (_Float16)0.f;
      }
      *(half8*)(xpH + ((size_t)nd * HWP + hw) * 512 + c0) = hi;
    }
  }
}

// ---------------- attn dots: dot[nd][o][hw] = qw[o] . xp_hi[hw]  (4 lanes per hw) ----------------
__global__ __launch_bounds__(256) void attn_dots(
    const float* __restrict__ Wq, const float* __restrict__ Wk,
    const float* __restrict__ xm,
    const _Float16* __restrict__ xpH, float* __restrict__ dotb) {
  int b = blockIdx.x;
  int nd = b >> 2, ch = b & 3;
  int t = threadIdx.x;
  __shared__ float xs[512];
  __shared__ float qsA[32];
  __shared__ float qw[2048];
  xs[t] = xm[nd * 512 + t];
  xs[t + 256] = xm[nd * 512 + t + 256];
  __syncthreads();
  {
    int k = t >> 3, j = t & 7;
    float p = 0.f;
    #pragma unroll 8
    for (int c = j; c < 512; c += 8) p = fmaf(Wq[k * 512 + c], xs[c], p);
    p += __shfl_xor(p, 4, 8);
    p += __shfl_xor(p, 2, 8);
    p += __shfl_xor(p, 1, 8);
    if (j == 0) qsA[k] = p;
  }
  __syncthreads();
  {
    int o = t >> 6;
    int c0 = (t & 63) * 8;
    float q[8];
    #pragma unroll
    for (int kd = 0; kd < 8; ++kd) q[kd] = qsA[o * 8 + kd];
    #pragma unroll
    for (int e = 0; e < 8; ++e) {
      float a = 0.f;
      #pragma unroll
      for (int kd = 0; kd < 8; ++kd)
        a = fmaf(q[kd], Wk[(size_t)(o * 8 + kd) * 512 + c0 + e], a);
      qw[o * 512 + c0 + e] = a;
    }
  }
  __syncthreads();
  if (t < 224) {
    int hwl = t >> 2, q = t & 3;
    int hw = ch * 56 + hwl;
    const _Float16* rh = xpH + ((size_t)nd * HWP + hw) * 512;
    float d0 = 0.f, d1 = 0.f, d2 = 0.f, d3 = 0.f;
    #pragma unroll
    for (int k = 0; k < 16; ++k) {
      int cb = q * 8 + k * 32;           // interleaved c-blocks: conflict-free qw banks
      half8 h = *(const half8*)(rh + cb);
      #pragma unroll
      for (int e = 0; e < 8; ++e) {
        float xv = (float)h[e];
        d0 = fmaf(qw[cb + e], xv, d0);
        d1 = fmaf(qw[512 + cb + e], xv, d1);
        d2 = fmaf(qw[1024 + cb + e], xv, d2);
        d3 = fmaf(qw[1536 + cb + e], xv, d3);
      }
    }
    d0 += __shfl_xor(d0, 1, 4); d0 += __shfl_xor(d0, 2, 4);
    d1 += __shfl_xor(d1, 1, 4); d1 += __shfl_xor(d1, 2, 4);
    d2 += __shfl_xor(d2, 1, 4); d2 += __shfl_xor(d2, 2, 4);
    d3 += __shfl_xor(d3, 1, 4); d3 += __shfl_xor(d3, 2, 4);
    float r = (q == 0) ? d0 : (q == 1) ? d1 : (q == 2) ? d2 : d3;
    dotb[((size_t)nd * 4 + q) * HWP + hw] = r * TEMP;
  }
}

// ---------------- moments + inline softmax + attention-weighted sum (2-product f16 MFMA) ----------
// Depth-2 pipeline on BOTH operands:
//  - B: 3 LDS buffers, stage(kk+2) issued at bottom of iter kk (4 gload_lds per wave).
//  - A: 2 register slots, A(kk+1) issued at TOP of iter kk (8 loads per wave) — one full MFMA
//    phase of cover, so the compiler's implicit reg-dependency wait is already satisfied.
// Ledger (per wave, per iter region): 8 A + 4 stage = 12 ->
//  barrier-A waits vmcnt(8) at kk=0 (newest = A(1)), vmcnt(12) steady, vmcnt(0) at kk=15.
__global__ __launch_bounds__(256, 2) void moments_mfma(
    const _Float16* __restrict__ WvA, const _Float16* __restrict__ xpH,
    const float* __restrict__ dotb, float* __restrict__ attn_out,
    float* __restrict__ S1, float* __restrict__ S2, float* __restrict__ S3) {
  int bid = blockIdx.x;
  int ob = (bid >> 3) & 15;
  int nd = ((bid >> 7) << 3) | (bid & 7);
  int o = ob >> 2;
  int t = threadIdx.x;
  int w = t >> 6, lane = t & 63;
  int wq = w >> 1, wh = w & 1;
  int rbase = ob * 8 + wq * 4;
  int jbase = wh * 7;
  int nj = 7 - wh;               // 7 for wh=0, 6 for wh=1
  __shared__ char ldsb[39936];   // 3 x 13312 B buffers: [j(13)][granule(64)][16B]
  __shared__ float attn_sh[HWP];
  __shared__ float redm[4];
  __shared__ float reds[4];
  const _Float16* xph = xpH + (size_t)nd * HWP * 512;

  // 1 vmem: dot row load (latency hides under staging)
  float vdot = (t < HW) ? dotb[((size_t)nd * 4 + o) * HWP + t] : -3.0e38f;

  f32x4 acc[4][7];
  #pragma unroll
  for (int f = 0; f < 4; ++f)
    #pragma unroll
    for (int j = 0; j < 7; ++j) acc[f][j] = (f32x4){0.f, 0.f, 0.f, 0.f};

  // stage one 13312B B-tile: every wave issues exactly 4 gload_lds instructions
  auto stage = [&](char* buf, int kk) {
    #pragma unroll
    for (int i = 0; i < 3; ++i) {
      int G = i * 256 + t;
      int j = G >> 6, g = G & 63;
      int hwl = g & 15, bb = g >> 4;
      const _Float16* src = xph + (size_t)(j * 16 + hwl) * 512 + kk * 32 + bb * 8;
      gload_lds16((const void*)src, (void*)(buf + G * 16));
    }
    if (lane < 16) {                       // round 3: 16 granules per wave
      int G = 768 + w * 16 + lane;
      int g = G & 63;
      int hwl = g & 15, bb = g >> 4;
      const _Float16* src = xph + (size_t)(12 * 16 + hwl) * 512 + kk * 32 + bb * 8;
      gload_lds16((const void*)src, (void*)(buf + G * 16));
    }
  };

  stage(ldsb, 0);                          // buf0: 4 vmem/wave
  __builtin_amdgcn_sched_barrier(0);       // pin: ops below stay below buf0's stages
  stage(ldsb + 13312, 1);                  // buf1: 4
  half8 Ah0[4], Al0[4], Ah1[4], Al1[4];    // two named A slots (no dynamic indexing)
  #pragma unroll
  for (int f = 0; f < 4; ++f) {            // A(0) -> slot0: 8 vmem
    Ah0[f] = *(const half8*)(WvA + ((size_t)0 * 128 + rbase + f) * 512 + lane * 8);
    Al0[f] = *(const half8*)(WvA + ((size_t)1 * 128 + rbase + f) * 512 + lane * 8);
  }

  // ---- inline softmax (exact division); lgkm-only barriers keep stage loads in flight ----
  {
    float m = vdot;
    #pragma unroll
    for (int off = 32; off; off >>= 1) m = fmaxf(m, __shfl_xor(m, off, 64));
    if (lane == 0) redm[w] = m;
    asm volatile("s_waitcnt lgkmcnt(0)" ::: "memory");
    __builtin_amdgcn_s_barrier();
    float bm = fmaxf(fmaxf(redm[0], redm[1]), fmaxf(redm[2], redm[3]));
    float e = (t < HW) ? expf(vdot - bm) : 0.f;
    float s = e;
    #pragma unroll
    for (int off = 32; off; off >>= 1) s += __shfl_xor(s, off, 64);
    if (lane == 0) reds[w] = s;
    asm volatile("s_waitcnt lgkmcnt(0)" ::: "memory");
    __builtin_amdgcn_s_barrier();
    float bs = reds[0] + reds[1] + reds[2] + reds[3];
    float a = (t < HW) ? (e / bs) : 0.f;
    if (t < HWP) attn_sh[t] = a;
    if ((ob & 3) == 0 && t < HW) {
      int n = nd >> 5, d = nd & 31;
      attn_out[(((size_t)n * 4 + o) * 32 + d) * HW + t] = a;   // +1 vmem store (block-uniform)
    }
  }

  // ---- main pipelined loop ----
  #pragma unroll
  for (int kk = 0; kk < 16; ++kk) {
    const bool even = (kk & 1) == 0;
    if (kk < 15) {
      // issue A(kk+1) into the alternate slot — consumed one iteration later
      #pragma unroll
      for (int f = 0; f < 4; ++f) {
        half8 h = *(const half8*)(WvA + ((size_t)((kk + 1) * 2 + 0) * 128 + rbase + f) * 512 + lane * 8);
        half8 l = *(const half8*)(WvA + ((size_t)((kk + 1) * 2 + 1) * 128 + rbase + f) * 512 + lane * 8);
        if (even) { Ah1[f] = h; Al1[f] = l; } else { Ah0[f] = h; Al0[f] = l; }
      }
    }
    if (kk == 0) {
      asm volatile("s_waitcnt vmcnt(8) lgkmcnt(0)" ::: "memory");
    } else if (kk == 15) {
      asm volatile("s_waitcnt vmcnt(0) lgkmcnt(0)" ::: "memory");
    } else {
      asm volatile("s_waitcnt vmcnt(12) lgkmcnt(0)" ::: "memory");
    }
    __builtin_amdgcn_s_barrier();
    __builtin_amdgcn_sched_barrier(0);
    __builtin_amdgcn_s_setprio(1);
    const char* bp = ldsb + (kk % 3) * 13312;
    #pragma unroll
    for (int j = 0; j < 7; ++j) {
      if (j < nj) {
        half8 bh = *(const half8*)(bp + (jbase + j) * 1024 + lane * 16);
        #pragma unroll
        for (int f = 0; f < 4; ++f) {
          acc[f][j] = MFMAH(even ? Ah0[f] : Ah1[f], bh, acc[f][j]);
          acc[f][j] = MFMAH(even ? Al0[f] : Al1[f], bh, acc[f][j]);
        }
      }
    }
    __builtin_amdgcn_s_setprio(0);
    __builtin_amdgcn_sched_barrier(0);
    asm volatile("s_waitcnt lgkmcnt(0)" ::: "memory");
    __builtin_amdgcn_s_barrier();
    if (kk < 14) stage(ldsb + ((kk + 2) % 3) * 13312, kk + 2);   // 4 vmem
  }

  // epilogue: S1, S2, S3. C/D layout: hw-col = lane&15, oc-row = (lane>>4)*4+r
  float attw[7];
  #pragma unroll
  for (int j = 0; j < 7; ++j) attw[j] = attn_sh[(jbase + j) * 16 + (lane & 15)];
  float* red = (float*)ldsb;    // overlay: all B-buffers dead after final barrier-B
  float q1[4][4], q2[4][4], q3[4][4];
  #pragma unroll
  for (int f = 0; f < 4; ++f) {
    #pragma unroll
    for (int r = 0; r < 4; ++r) {
      float u = 0.f, vsq = 0.f, wsum = 0.f;
      #pragma unroll
      for (int j = 0; j < 7; ++j) {
        float v = acc[f][j][r];
        u += v;
        vsq = fmaf(v, v, vsq);
        wsum = fmaf(v, attw[j], wsum);
      }
      #pragma unroll
      for (int off = 8; off; off >>= 1) {
        u += __shfl_xor(u, off, 16);
        vsq += __shfl_xor(vsq, off, 16);
        wsum += __shfl_xor(wsum, off, 16);
      }
      q1[f][r] = u; q2[f][r] = vsq; q3[f][r] = wsum;
    }
  }
  int rowq = lane >> 4;
  bool wr = (lane & 15) == 0;
  if (wh == 0 && wr) {
    #pragma unroll
    for (int f = 0; f < 4; ++f)
      #pragma unroll
      for (int r = 0; r < 4; ++r) {
        int idx = wq * 64 + f * 16 + rowq * 4 + r;
        red[idx] = q1[f][r];
        red[128 + idx] = q2[f][r];
        red[256 + idx] = q3[f][r];
      }
  }
  __syncthreads();
  if (wh == 1 && wr) {
    size_t base = (size_t)nd * OC + ob * 128 + wq * 64;
    #pragma unroll
    for (int f = 0; f < 4; ++f)
      #pragma unroll
      for (int r = 0; r < 4; ++r) {
        int idx = f * 16 + rowq * 4 + r;
        S1[base + idx] = red[wq * 64 + idx] + q1[f][r];
        S2[base + idx] = red[128 + wq * 64 + idx] + q2[f][r];
        S3[base + idx] = red[256 + wq * 64 + idx] + q3[f][r];
      }
  }
}

// ---------------- head: per (nd,oc) InstanceNorm + gelu + Wout reduce ----------------
__global__ void head_final(const float* __restrict__ S1, const float* __restrict__ S2,
                           const float* __restrict__ S3,
                           const float* __restrict__ gamma, const float* __restrict__ beta,
                           const float* __restrict__ Wout, const float* __restrict__ bout,
                           float* __restrict__ outs) {
  int nd = blockIdx.x;
  int t = threadIdx.x;
  int w = t >> 6, lane = t & 63;
  __shared__ float redp[16];
  float po[4] = {0.f, 0.f, 0.f, 0.f};
  #pragma unroll
  for (int i = 0; i < 8; ++i) {
    int oc = i * 256 + t;
    float m1 = S1[(size_t)nd * OC + oc] * INV196;
    float m2 = S2[(size_t)nd * OC + oc] * INV196;
    float var = m2 - m1 * m1;
    float rs = rsqrtf(var + 1e-5f);
    float xh = (S3[(size_t)nd * OC + oc] - m1) * rs * gamma[oc] + beta[oc];
    float ge = 0.5f * xh * (1.0f + erff(xh * 0.70710678118654752f));
    po[i >> 1] = fmaf(ge, Wout[oc], po[i >> 1]);
  }
  #pragma unroll
  for (int off = 32; off; off >>= 1) {
    #pragma unroll
    for (int o = 0; o < 4; ++o) po[o] += __shfl_down(po[o], off, 64);
  }
  if (lane == 0) {
    #pragma unroll
    for (int o = 0; o < 4; ++o) redp[w * 4 + o] = po[o];
  }
  __syncthreads();
  if (t < 4) {
    int o = t;
    float s = redp[o] + redp[4 + o] + redp[8 + o] + redp[12 + o] + bout[o];
    int n = nd >> 5, d = nd & 31;
    outs[o * 64 + n * 32 + d] = s;
  }
}

}  // namespace

extern "C" void kernel_launch(void* const* d_in, const int* in_sizes, int n_in,
                              void* d_out, int out_size, void* d_ws, size_t ws_size,
                              hipStream_t stream) {
  const float* x     = (const float*)d_in[0];
  const float* Wq    = (const float*)d_in[1];
  const float* Wk    = (const float*)d_in[2];
  const float* Wv    = (const float*)d_in[3];
  const float* gamma = (const float*)d_in[4];
  const float* beta  = (const float*)d_in[5];
  const float* Wout  = (const float*)d_in[6];
  const float* bout  = (const float*)d_in[7];
  float* out      = (float*)d_out;
  float* attn_out = out;            // (N,4,D,196) = 50176 floats
  float* outs     = out + 50176;    // (4,N,1,D)   = 256 floats

  float* ws = (float*)d_ws;
  _Float16*  WvA  = (_Float16*)ws;                      // 2097152 f16 -> [0, 1048576) floats
  _Float16*  xpH  = (_Float16*)(ws + 1048576);          // 7340032 f16 -> 3670016 floats
  float*     xm   = ws + 4718592;                       // 32768
  float*     dotb = ws + 4751360;                       // 57344
  float*     S1   = ws + 4808704;                       // 131072
  float*     S2   = ws + 4939776;                       // 131072
  float*     S3   = ws + 5070848;                       // 131072

  fat_prep<<<4608, 256, 0, stream>>>(x, Wv, WvA, xpH, xm);
  attn_dots<<<256, 256, 0, stream>>>(Wq, Wk, xm, xpH, dotb);
  moments_mfma<<<1024, 256, 0, stream>>>(WvA, xpH, dotb, attn_out, S1, S2, S3);
  head_final<<<64, 256, 0, stream>>>(S1, S2, S3, gamma, beta, Wout, bout, outs);
}

// Round 16
// 83.411 us; speedup vs baseline: 1.6947x; 1.6947x over previous
//
#include <hip/hip_runtime.h>
#include <math.h>

namespace {

constexpr int HW  = 196;
constexpr int HWP = 224;
constexpr int OC  = 2048;
constexpr float TEMP   = 0.35355339059327373f;  // 1/sqrt(KEY_DIM)
constexpr float INV196 = 1.0f / 196.0f;

typedef __attribute__((ext_vector_type(8))) _Float16 half8;
typedef __attribute__((ext_vector_type(4))) float f32x4;

__device__ __forceinline__ void gload_lds16(const void* g, void* l) {
  __builtin_amdgcn_global_load_lds(
      (const __attribute__((address_space(1))) void*)g,
      (__attribute__((address_space(3))) void*)l, 16, 0, 0);
}

#define MFMAH(a, b, c) __builtin_amdgcn_mfma_f32_16x16x32_f16((a), (b), (c), 0, 0, 0)

// ================= K1: WvA prep (512 blocks) || pool (4096 blocks, XCD-affine) =================
__global__ __launch_bounds__(256) void fat_prep(
    const float* __restrict__ x, const float* __restrict__ Wv,
    _Float16* __restrict__ WvA,
    _Float16* __restrict__ xpH, float* __restrict__ xm) {
  __shared__ float tl[8][264];
  int bid = blockIdx.x;
  int t = threadIdx.x;
  if (bid < 512) {
    int kk = bid >> 5;
    int rq = bid & 31;
    int w = t >> 6, lane = t & 63;
    int r = rq * 4 + w;
    int oc = r * 16 + (lane & 15);
    int c0 = kk * 32 + (lane >> 4) * 8;
    const float* src = Wv + (size_t)oc * 512 + c0;
    float4 v0 = *(const float4*)src;
    float4 v1 = *(const float4*)(src + 4);
    float vals[8] = {v0.x, v0.y, v0.z, v0.w, v1.x, v1.y, v1.z, v1.w};
    half8 hi, lo;
    #pragma unroll
    for (int e = 0; e < 8; ++e) {
      _Float16 h = (_Float16)vals[e];
      hi[e] = h;
      lo[e] = (_Float16)(vals[e] - (float)h);
    }
    *(half8*)(WvA + ((size_t)(kk * 2 + 0) * 128 + r) * 512 + lane * 8) = hi;
    *(half8*)(WvA + ((size_t)(kk * 2 + 1) * 128 + r) * 512 + lane * 8) = lo;
  } else {
    int pb = bid - 512;
    int nd = (((pb >> 9) & 7) << 3) | (pb & 7);   // XCD-affine
    int cg = (pb >> 3) & 63;
    int n = nd >> 5, d = nd & 31;
    int c0 = cg * 8;
    int cl = t >> 5, s = t & 31;
    const float* xr = x + (((size_t)(n * 512 + c0 + cl)) * 32 + d) * 256;
    float4 va = *(const float4*)(xr + s * 8);
    float4 vb = *(const float4*)(xr + s * 8 + 4);
    *(float4*)&tl[cl][s * 8] = va;
    *(float4*)&tl[cl][s * 8 + 4] = vb;
    float rs = va.x + va.y + va.z + va.w + vb.x + vb.y + vb.z + vb.w;
    #pragma unroll
    for (int off = 16; off; off >>= 1) rs += __shfl_xor(rs, off, 32);
    if (s == 0) xm[nd * 512 + c0 + cl] = rs * (1.0f / 256.0f);
    __syncthreads();
    if (t < HWP) {
      int hw = t;
      half8 hi;
      if (hw < HW) {
        int y = hw / 14, xx = hw - y * 14;
        #pragma unroll
        for (int c = 0; c < 8; ++c) {
          const float* q = &tl[c][y * 16 + xx];
          float val = (q[0] + q[1] + q[2] + q[16] + q[17] + q[18] +
                       q[32] + q[33] + q[34]) * (1.0f / 9.0f);
          hi[c] = (_Float16)val;
        }
      } else {
        #pragma unroll
        for (int c = 0; c < 8; ++c) hi[c] = (_Float16)0.f;
      }
      *(half8*)(xpH + ((size_t)nd * HWP + hw) * 512 + c0) = hi;
    }
  }
}

// ---------------- attn dots: dot[nd][o][hw] = qw[o] . xp_hi[hw]  (4 lanes per hw) ----------------
__global__ __launch_bounds__(256) void attn_dots(
    const float* __restrict__ Wq, const float* __restrict__ Wk,
    const float* __restrict__ xm,
    const _Float16* __restrict__ xpH, float* __restrict__ dotb) {
  int b = blockIdx.x;
  int nd = b >> 2, ch = b & 3;
  int t = threadIdx.x;
  __shared__ float xs[512];
  __shared__ float qsA[32];
  __shared__ float qw[2048];
  xs[t] = xm[nd * 512 + t];
  xs[t + 256] = xm[nd * 512 + t + 256];
  __syncthreads();
  {
    int k = t >> 3, j = t & 7;
    float p = 0.f;
    #pragma unroll 8
    for (int c = j; c < 512; c += 8) p = fmaf(Wq[k * 512 + c], xs[c], p);
    p += __shfl_xor(p, 4, 8);
    p += __shfl_xor(p, 2, 8);
    p += __shfl_xor(p, 1, 8);
    if (j == 0) qsA[k] = p;
  }
  __syncthreads();
  {
    int o = t >> 6;
    int c0 = (t & 63) * 8;
    float q[8];
    #pragma unroll
    for (int kd = 0; kd < 8; ++kd) q[kd] = qsA[o * 8 + kd];
    #pragma unroll
    for (int e = 0; e < 8; ++e) {
      float a = 0.f;
      #pragma unroll
      for (int kd = 0; kd < 8; ++kd)
        a = fmaf(q[kd], Wk[(size_t)(o * 8 + kd) * 512 + c0 + e], a);
      qw[o * 512 + c0 + e] = a;
    }
  }
  __syncthreads();
  if (t < 224) {
    int hwl = t >> 2, q = t & 3;
    int hw = ch * 56 + hwl;
    const _Float16* rh = xpH + ((size_t)nd * HWP + hw) * 512;
    float d0 = 0.f, d1 = 0.f, d2 = 0.f, d3 = 0.f;
    #pragma unroll
    for (int k = 0; k < 16; ++k) {
      int cb = q * 8 + k * 32;           // interleaved c-blocks: conflict-free qw banks
      half8 h = *(const half8*)(rh + cb);
      #pragma unroll
      for (int e = 0; e < 8; ++e) {
        float xv = (float)h[e];
        d0 = fmaf(qw[cb + e], xv, d0);
        d1 = fmaf(qw[512 + cb + e], xv, d1);
        d2 = fmaf(qw[1024 + cb + e], xv, d2);
        d3 = fmaf(qw[1536 + cb + e], xv, d3);
      }
    }
    d0 += __shfl_xor(d0, 1, 4); d0 += __shfl_xor(d0, 2, 4);
    d1 += __shfl_xor(d1, 1, 4); d1 += __shfl_xor(d1, 2, 4);
    d2 += __shfl_xor(d2, 1, 4); d2 += __shfl_xor(d2, 2, 4);
    d3 += __shfl_xor(d3, 1, 4); d3 += __shfl_xor(d3, 2, 4);
    float r = (q == 0) ? d0 : (q == 1) ? d1 : (q == 2) ? d2 : d3;
    dotb[((size_t)nd * 4 + q) * HWP + hw] = r * TEMP;
  }
}

// ---------------- moments + inline softmax + attention-weighted sum (2-product f16 MFMA) ----------
// Wave = 2 oc-rows x all 13 j  (acc 26 f32x4 = 104 AGPR; A slots 32 VGPR — fits (256,2), no spill).
// A prefetched 2 regions ahead into parity slots (direct loads, no temps); B: 2 LDS buffers,
// stage(kk+2) -> buf(kk&1) after barrier-B drains its readers.
// Ledger: region kk = [4 stage(kk+2), 4 A(kk+2)]. barrier-A(kk): vmcnt(12) (kk<=14), vmcnt(4) (kk=15);
// A(kk) covered by implicit reg-dependency waits with 2-region slack.
__global__ __launch_bounds__(256, 2) void moments_mfma(
    const _Float16* __restrict__ WvA, const _Float16* __restrict__ xpH,
    const float* __restrict__ dotb, float* __restrict__ attn_out,
    float* __restrict__ S1, float* __restrict__ S2, float* __restrict__ S3) {
  int bid = blockIdx.x;
  int ob = (bid >> 3) & 15;
  int nd = ((bid >> 7) << 3) | (bid & 7);
  int o = ob >> 2;
  int t = threadIdx.x;
  int w = t >> 6, lane = t & 63;
  int rbase = ob * 8 + w * 2;            // this wave's 2 oc-rows
  __shared__ char ldsb[26624];           // 2 x 13312 B buffers: [j(13)][granule(64)][16B]
  __shared__ float attn_sh[HWP];
  __shared__ float redm[4];
  __shared__ float reds[4];
  const _Float16* xph = xpH + (size_t)nd * HWP * 512;

  float vdot = (t < HW) ? dotb[((size_t)nd * 4 + o) * HWP + t] : -3.0e38f;

  f32x4 acc[2][13];
  #pragma unroll
  for (int f = 0; f < 2; ++f)
    #pragma unroll
    for (int j = 0; j < 13; ++j) acc[f][j] = (f32x4){0.f, 0.f, 0.f, 0.f};

  // stage one 13312B B-tile: every wave issues exactly 4 gload_lds instructions
  auto stage = [&](char* buf, int kk) {
    #pragma unroll
    for (int i = 0; i < 3; ++i) {
      int G = i * 256 + t;
      int j = G >> 6, g = G & 63;
      int hwl = g & 15, bb = g >> 4;
      const _Float16* src = xph + (size_t)(j * 16 + hwl) * 512 + kk * 32 + bb * 8;
      gload_lds16((const void*)src, (void*)(buf + G * 16));
    }
    if (lane < 16) {
      int G = 768 + w * 16 + lane;
      int g = G & 63;
      int hwl = g & 15, bb = g >> 4;
      const _Float16* src = xph + (size_t)(12 * 16 + hwl) * 512 + kk * 32 + bb * 8;
      gload_lds16((const void*)src, (void*)(buf + G * 16));
    }
  };

  stage(ldsb, 0);                        // 4 vmem/wave
  __builtin_amdgcn_sched_barrier(0);
  stage(ldsb + 13312, 1);                // 4
  half8 Ah0[2], Al0[2], Ah1[2], Al1[2];
  #pragma unroll
  for (int f = 0; f < 2; ++f) {          // A(0) -> slot0: 4 vmem
    Ah0[f] = *(const half8*)(WvA + ((size_t)(0 * 2 + 0) * 128 + rbase + f) * 512 + lane * 8);
    Al0[f] = *(const half8*)(WvA + ((size_t)(0 * 2 + 1) * 128 + rbase + f) * 512 + lane * 8);
  }
  #pragma unroll
  for (int f = 0; f < 2; ++f) {          // A(1) -> slot1: 4 vmem
    Ah1[f] = *(const half8*)(WvA + ((size_t)(1 * 2 + 0) * 128 + rbase + f) * 512 + lane * 8);
    Al1[f] = *(const half8*)(WvA + ((size_t)(1 * 2 + 1) * 128 + rbase + f) * 512 + lane * 8);
  }

  // ---- inline softmax (exact division); lgkm-only barriers keep vmem loads in flight ----
  {
    float m = vdot;
    #pragma unroll
    for (int off = 32; off; off >>= 1) m = fmaxf(m, __shfl_xor(m, off, 64));
    if (lane == 0) redm[w] = m;
    asm volatile("s_waitcnt lgkmcnt(0)" ::: "memory");
    __builtin_amdgcn_s_barrier();
    float bm = fmaxf(fmaxf(redm[0], redm[1]), fmaxf(redm[2], redm[3]));
    float e = (t < HW) ? expf(vdot - bm) : 0.f;
    float s = e;
    #pragma unroll
    for (int off = 32; off; off >>= 1) s += __shfl_xor(s, off, 64);
    if (lane == 0) reds[w] = s;
    asm volatile("s_waitcnt lgkmcnt(0)" ::: "memory");
    __builtin_amdgcn_s_barrier();
    float bs = reds[0] + reds[1] + reds[2] + reds[3];
    float a = (t < HW) ? (e / bs) : 0.f;
    if (t < HWP) attn_sh[t] = a;
    if ((ob & 3) == 0 && t < HW) {
      int n = nd >> 5, d = nd & 31;
      attn_out[(((size_t)n * 4 + o) * 32 + d) * HW + t] = a;
    }
  }

  // ---- main pipelined loop ----
  #pragma unroll
  for (int kk = 0; kk < 16; ++kk) {
    if (kk == 15) {
      asm volatile("s_waitcnt vmcnt(4) lgkmcnt(0)" ::: "memory");
    } else {
      asm volatile("s_waitcnt vmcnt(12) lgkmcnt(0)" ::: "memory");
    }
    __builtin_amdgcn_s_barrier();
    __builtin_amdgcn_sched_barrier(0);
    __builtin_amdgcn_s_setprio(1);
    const char* bp = ldsb + (kk & 1) * 13312;
    if ((kk & 1) == 0) {
      #pragma unroll
      for (int j = 0; j < 13; ++j) {
        half8 bh = *(const half8*)(bp + j * 1024 + lane * 16);
        acc[0][j] = MFMAH(Ah0[0], bh, acc[0][j]);
        acc[0][j] = MFMAH(Al0[0], bh, acc[0][j]);
        acc[1][j] = MFMAH(Ah0[1], bh, acc[1][j]);
        acc[1][j] = MFMAH(Al0[1], bh, acc[1][j]);
      }
    } else {
      #pragma unroll
      for (int j = 0; j < 13; ++j) {
        half8 bh = *(const half8*)(bp + j * 1024 + lane * 16);
        acc[0][j] = MFMAH(Ah1[0], bh, acc[0][j]);
        acc[0][j] = MFMAH(Al1[0], bh, acc[0][j]);
        acc[1][j] = MFMAH(Ah1[1], bh, acc[1][j]);
        acc[1][j] = MFMAH(Al1[1], bh, acc[1][j]);
      }
    }
    __builtin_amdgcn_s_setprio(0);
    __builtin_amdgcn_sched_barrier(0);
    asm volatile("s_waitcnt lgkmcnt(0)" ::: "memory");
    __builtin_amdgcn_s_barrier();
    if (kk < 14) {
      stage(ldsb + (kk & 1) * 13312, kk + 2);          // 4 vmem
      if ((kk & 1) == 0) {                             // A(kk+2) -> slot0: 4 vmem
        #pragma unroll
        for (int f = 0; f < 2; ++f) {
          Ah0[f] = *(const half8*)(WvA + ((size_t)((kk + 2) * 2 + 0) * 128 + rbase + f) * 512 + lane * 8);
          Al0[f] = *(const half8*)(WvA + ((size_t)((kk + 2) * 2 + 1) * 128 + rbase + f) * 512 + lane * 8);
        }
      } else {                                         // A(kk+2) -> slot1
        #pragma unroll
        for (int f = 0; f < 2; ++f) {
          Ah1[f] = *(const half8*)(WvA + ((size_t)((kk + 2) * 2 + 0) * 128 + rbase + f) * 512 + lane * 8);
          Al1[f] = *(const half8*)(WvA + ((size_t)((kk + 2) * 2 + 1) * 128 + rbase + f) * 512 + lane * 8);
        }
      }
    }
  }

  // epilogue: per-wave direct S1/S2/S3 (no cross-wave reduction needed).
  // C/D layout: hw-col = lane&15, oc-row-in-frag = (lane>>4)*4 + r.
  float attw[13];
  #pragma unroll
  for (int j = 0; j < 13; ++j) attw[j] = attn_sh[j * 16 + (lane & 15)];
  #pragma unroll
  for (int f = 0; f < 2; ++f) {
    #pragma unroll
    for (int r = 0; r < 4; ++r) {
      float u = 0.f, vsq = 0.f, wsum = 0.f;
      #pragma unroll
      for (int j = 0; j < 13; ++j) {
        float v = acc[f][j][r];
        u += v;
        vsq = fmaf(v, v, vsq);
        wsum = fmaf(v, attw[j], wsum);
      }
      #pragma unroll
      for (int off = 8; off; off >>= 1) {
        u += __shfl_xor(u, off, 16);
        vsq += __shfl_xor(vsq, off, 16);
        wsum += __shfl_xor(wsum, off, 16);
      }
      if ((lane & 15) == 0) {
        int oc = (rbase + f) * 16 + (lane >> 4) * 4 + r;
        size_t base = (size_t)nd * OC + oc;
        S1[base] = u;
        S2[base] = vsq;
        S3[base] = wsum;
      }
    }
  }
}

// ---------------- head: per (nd,oc) InstanceNorm + gelu + Wout reduce ----------------
__global__ void head_final(const float* __restrict__ S1, const float* __restrict__ S2,
                           const float* __restrict__ S3,
                           const float* __restrict__ gamma, const float* __restrict__ beta,
                           const float* __restrict__ Wout, const float* __restrict__ bout,
                           float* __restrict__ outs) {
  int nd = blockIdx.x;
  int t = threadIdx.x;
  int w = t >> 6, lane = t & 63;
  __shared__ float redp[16];
  float po[4] = {0.f, 0.f, 0.f, 0.f};
  #pragma unroll
  for (int i = 0; i < 8; ++i) {
    int oc = i * 256 + t;
    float m1 = S1[(size_t)nd * OC + oc] * INV196;
    float m2 = S2[(size_t)nd * OC + oc] * INV196;
    float var = m2 - m1 * m1;
    float rs = rsqrtf(var + 1e-5f);
    float xh = (S3[(size_t)nd * OC + oc] - m1) * rs * gamma[oc] + beta[oc];
    float ge = 0.5f * xh * (1.0f + erff(xh * 0.70710678118654752f));
    po[i >> 1] = fmaf(ge, Wout[oc], po[i >> 1]);
  }
  #pragma unroll
  for (int off = 32; off; off >>= 1) {
    #pragma unroll
    for (int o = 0; o < 4; ++o) po[o] += __shfl_down(po[o], off, 64);
  }
  if (lane == 0) {
    #pragma unroll
    for (int o = 0; o < 4; ++o) redp[w * 4 + o] = po[o];
  }
  __syncthreads();
  if (t < 4) {
    int o = t;
    float s = redp[o] + redp[4 + o] + redp[8 + o] + redp[12 + o] + bout[o];
    int n = nd >> 5, d = nd & 31;
    outs[o * 64 + n * 32 + d] = s;
  }
}

}  // namespace

extern "C" void kernel_launch(void* const* d_in, const int* in_sizes, int n_in,
                              void* d_out, int out_size, void* d_ws, size_t ws_size,
                              hipStream_t stream) {
  const float* x     = (const float*)d_in[0];
  const float* Wq    = (const float*)d_in[1];
  const float* Wk    = (const float*)d_in[2];
  const float* Wv    = (const float*)d_in[3];
  const float* gamma = (const float*)d_in[4];
  const float* beta  = (const float*)d_in[5];
  const float* Wout  = (const float*)d_in[6];
  const float* bout  = (const float*)d_in[7];
  float* out      = (float*)d_out;
  float* attn_out = out;            // (N,4,D,196) = 50176 floats
  float* outs     = out + 50176;    // (4,N,1,D)   = 256 floats

  float* ws = (float*)d_ws;
  _Float16*  WvA  = (_Float16*)ws;                      // 2097152 f16 -> [0, 1048576) floats
  _Float16*  xpH  = (_Float16*)(ws + 1048576);          // 7340032 f16 -> 3670016 floats
  float*     xm   = ws + 4718592;                       // 32768
  float*     dotb = ws + 4751360;                       // 57344
  float*     S1   = ws + 4808704;                       // 131072
  float*     S2   = ws + 4939776;                       // 131072
  float*     S3   = ws + 5070848;                       // 131072

  fat_prep<<<4608, 256, 0, stream>>>(x, Wv, WvA, xpH, xm);
  attn_dots<<<256, 256, 0, stream>>>(Wq, Wk, xm, xpH, dotb);
  moments_mfma<<<1024, 256, 0, stream>>>(WvA, xpH, dotb, attn_out, S1, S2, S3);
  head_final<<<64, 256, 0, stream>>>(S1, S2, S3, gamma, beta, Wout, bout, outs);
}

// Round 17
// 71.978 us; speedup vs baseline: 1.9638x; 1.1588x over previous
//
#include <hip/hip_runtime.h>
#include <math.h>

namespace {

constexpr int HW  = 196;
constexpr int HWP = 224;
constexpr int OC  = 2048;
constexpr float TEMP   = 0.35355339059327373f;  // 1/sqrt(KEY_DIM)
constexpr float INV196 = 1.0f / 196.0f;

typedef __attribute__((ext_vector_type(8))) _Float16 half8;
typedef __attribute__((ext_vector_type(4))) float f32x4;

__device__ __forceinline__ void gload_lds16(const void* g, void* l) {
  __builtin_amdgcn_global_load_lds(
      (const __attribute__((address_space(1))) void*)g,
      (__attribute__((address_space(3))) void*)l, 16, 0, 0);
}

#define MFMAH(a, b, c) __builtin_amdgcn_mfma_f32_16x16x32_f16((a), (b), (c), 0, 0, 0)

// ================= K1: WvA prep (512 blocks) || pool (4096 blocks, XCD-affine) =================
__global__ __launch_bounds__(256) void fat_prep(
    const float* __restrict__ x, const float* __restrict__ Wv,
    _Float16* __restrict__ WvA,
    _Float16* __restrict__ xpH, float* __restrict__ xm) {
  __shared__ float tl[8][264];
  int bid = blockIdx.x;
  int t = threadIdx.x;
  if (bid < 512) {
    int kk = bid >> 5;
    int rq = bid & 31;
    int w = t >> 6, lane = t & 63;
    int r = rq * 4 + w;
    int oc = r * 16 + (lane & 15);
    int c0 = kk * 32 + (lane >> 4) * 8;
    const float* src = Wv + (size_t)oc * 512 + c0;
    float4 v0 = *(const float4*)src;
    float4 v1 = *(const float4*)(src + 4);
    float vals[8] = {v0.x, v0.y, v0.z, v0.w, v1.x, v1.y, v1.z, v1.w};
    half8 hi, lo;
    #pragma unroll
    for (int e = 0; e < 8; ++e) {
      _Float16 h = (_Float16)vals[e];
      hi[e] = h;
      lo[e] = (_Float16)(vals[e] - (float)h);
    }
    *(half8*)(WvA + ((size_t)(kk * 2 + 0) * 128 + r) * 512 + lane * 8) = hi;
    *(half8*)(WvA + ((size_t)(kk * 2 + 1) * 128 + r) * 512 + lane * 8) = lo;
  } else {
    int pb = bid - 512;
    int nd = (((pb >> 9) & 7) << 3) | (pb & 7);   // XCD-affine
    int cg = (pb >> 3) & 63;
    int n = nd >> 5, d = nd & 31;
    int c0 = cg * 8;
    int cl = t >> 5, s = t & 31;
    const float* xr = x + (((size_t)(n * 512 + c0 + cl)) * 32 + d) * 256;
    float4 va = *(const float4*)(xr + s * 8);
    float4 vb = *(const float4*)(xr + s * 8 + 4);
    *(float4*)&tl[cl][s * 8] = va;
    *(float4*)&tl[cl][s * 8 + 4] = vb;
    float rs = va.x + va.y + va.z + va.w + vb.x + vb.y + vb.z + vb.w;
    #pragma unroll
    for (int off = 16; off; off >>= 1) rs += __shfl_xor(rs, off, 32);
    if (s == 0) xm[nd * 512 + c0 + cl] = rs * (1.0f / 256.0f);
    __syncthreads();
    if (t < HWP) {
      int hw = t;
      half8 hi;
      if (hw < HW) {
        int y = hw / 14, xx = hw - y * 14;
        #pragma unroll
        for (int c = 0; c < 8; ++c) {
          const float* q = &tl[c][y * 16 + xx];
          float val = (q[0] + q[1] + q[2] + q[16] + q[17] + q[18] +
                       q[32] + q[33] + q[34]) * (1.0f / 9.0f);
          hi[c] = (_Float16)val;
        }
      } else {
        #pragma unroll
        for (int c = 0; c < 8; ++c) hi[c] = (_Float16)0.f;
      }
      *(half8*)(xpH + ((size_t)nd * HWP + hw) * 512 + c0) = hi;
    }
  }
}

// ---------------- attn dots: dot[nd][o][hw] = qw[o] . xp_hi[hw]  (4 lanes per hw) ----------------
__global__ __launch_bounds__(256) void attn_dots(
    const float* __restrict__ Wq, const float* __restrict__ Wk,
    const float* __restrict__ xm,
    const _Float16* __restrict__ xpH, float* __restrict__ dotb) {
  int b = blockIdx.x;
  int nd = b >> 2, ch = b & 3;
  int t = threadIdx.x;
  __shared__ float xs[512];
  __shared__ float qsA[32];
  __shared__ float qw[2048];
  xs[t] = xm[nd * 512 + t];
  xs[t + 256] = xm[nd * 512 + t + 256];
  __syncthreads();
  {
    int k = t >> 3, j = t & 7;
    float p = 0.f;
    #pragma unroll 8
    for (int c = j; c < 512; c += 8) p = fmaf(Wq[k * 512 + c], xs[c], p);
    p += __shfl_xor(p, 4, 8);
    p += __shfl_xor(p, 2, 8);
    p += __shfl_xor(p, 1, 8);
    if (j == 0) qsA[k] = p;
  }
  __syncthreads();
  {
    int o = t >> 6;
    int c0 = (t & 63) * 8;
    float q[8];
    #pragma unroll
    for (int kd = 0; kd < 8; ++kd) q[kd] = qsA[o * 8 + kd];
    #pragma unroll
    for (int e = 0; e < 8; ++e) {
      float a = 0.f;
      #pragma unroll
      for (int kd = 0; kd < 8; ++kd)
        a = fmaf(q[kd], Wk[(size_t)(o * 8 + kd) * 512 + c0 + e], a);
      qw[o * 512 + c0 + e] = a;
    }
  }
  __syncthreads();
  if (t < 224) {
    int hwl = t >> 2, q = t & 3;
    int hw = ch * 56 + hwl;
    const _Float16* rh = xpH + ((size_t)nd * HWP + hw) * 512;
    float d0 = 0.f, d1 = 0.f, d2 = 0.f, d3 = 0.f;
    #pragma unroll
    for (int k = 0; k < 16; ++k) {
      int cb = q * 8 + k * 32;           // interleaved c-blocks: conflict-free qw banks
      half8 h = *(const half8*)(rh + cb);
      #pragma unroll
      for (int e = 0; e < 8; ++e) {
        float xv = (float)h[e];
        d0 = fmaf(qw[cb + e], xv, d0);
        d1 = fmaf(qw[512 + cb + e], xv, d1);
        d2 = fmaf(qw[1024 + cb + e], xv, d2);
        d3 = fmaf(qw[1536 + cb + e], xv, d3);
      }
    }
    d0 += __shfl_xor(d0, 1, 4); d0 += __shfl_xor(d0, 2, 4);
    d1 += __shfl_xor(d1, 1, 4); d1 += __shfl_xor(d1, 2, 4);
    d2 += __shfl_xor(d2, 1, 4); d2 += __shfl_xor(d2, 2, 4);
    d3 += __shfl_xor(d3, 1, 4); d3 += __shfl_xor(d3, 2, 4);
    float r = (q == 0) ? d0 : (q == 1) ? d1 : (q == 2) ? d2 : d3;
    dotb[((size_t)nd * 4 + q) * HWP + hw] = r * TEMP;
  }
}

// ---------------- moments + inline softmax + attention-weighted sum (1-product f16 MFMA) ----------
// A-lo product DELETED: B (xp) is f16 hi-only (eps_B~2.8e-4, measured out-1 absmax 3.8e-6 in r12);
// dropping A-lo raises elementwise error by only sqrt(2) -> predicted out-1 ~5e-6, 30x margin.
// Wave = 2 oc-rows x all 13 j (acc 104 AGPR; A slots 16 VGPR). A prefetched 2 regions ahead into
// parity slots; B: 2 LDS buffers, stage(kk+2)->buf(kk&1).
// Ledger (per wave): prologue = stage0(4), stage1(4), A0(2), A1(2) [+1 attn store, some blocks].
// Region kk bottom = stage(kk+2)x4, A(kk+2)x2. barrier-A(kk): vmcnt(6) retires stage(kk)+A(kk)
// leaving stage(kk+1)+A(kk+1)=6 (kk=0/1 drain verified incl. store). kk=15: vmcnt(0).
__global__ __launch_bounds__(256, 2) void moments_mfma(
    const _Float16* __restrict__ WvA, const _Float16* __restrict__ xpH,
    const float* __restrict__ dotb, float* __restrict__ attn_out,
    float* __restrict__ S1, float* __restrict__ S2, float* __restrict__ S3) {
  int bid = blockIdx.x;
  int ob = (bid >> 3) & 15;
  int nd = ((bid >> 7) << 3) | (bid & 7);
  int o = ob >> 2;
  int t = threadIdx.x;
  int w = t >> 6, lane = t & 63;
  int rbase = ob * 8 + w * 2;            // this wave's 2 oc-rows
  __shared__ char ldsb[26624];           // 2 x 13312 B buffers: [j(13)][granule(64)][16B]
  __shared__ float attn_sh[HWP];
  __shared__ float redm[4];
  __shared__ float reds[4];
  const _Float16* xph = xpH + (size_t)nd * HWP * 512;

  float vdot = (t < HW) ? dotb[((size_t)nd * 4 + o) * HWP + t] : -3.0e38f;

  f32x4 acc[2][13];
  #pragma unroll
  for (int f = 0; f < 2; ++f)
    #pragma unroll
    for (int j = 0; j < 13; ++j) acc[f][j] = (f32x4){0.f, 0.f, 0.f, 0.f};

  // stage one 13312B B-tile: every wave issues exactly 4 gload_lds instructions
  auto stage = [&](char* buf, int kk) {
    #pragma unroll
    for (int i = 0; i < 3; ++i) {
      int G = i * 256 + t;
      int j = G >> 6, g = G & 63;
      int hwl = g & 15, bb = g >> 4;
      const _Float16* src = xph + (size_t)(j * 16 + hwl) * 512 + kk * 32 + bb * 8;
      gload_lds16((const void*)src, (void*)(buf + G * 16));
    }
    if (lane < 16) {
      int G = 768 + w * 16 + lane;
      int g = G & 63;
      int hwl = g & 15, bb = g >> 4;
      const _Float16* src = xph + (size_t)(12 * 16 + hwl) * 512 + kk * 32 + bb * 8;
      gload_lds16((const void*)src, (void*)(buf + G * 16));
    }
  };

  stage(ldsb, 0);                        // 4 vmem/wave
  __builtin_amdgcn_sched_barrier(0);
  stage(ldsb + 13312, 1);                // 4
  half8 Ah0[2], Ah1[2];
  #pragma unroll
  for (int f = 0; f < 2; ++f)            // A(0) hi -> slot0: 2 vmem
    Ah0[f] = *(const half8*)(WvA + ((size_t)(0 * 2 + 0) * 128 + rbase + f) * 512 + lane * 8);
  #pragma unroll
  for (int f = 0; f < 2; ++f)            // A(1) hi -> slot1: 2 vmem
    Ah1[f] = *(const half8*)(WvA + ((size_t)(1 * 2 + 0) * 128 + rbase + f) * 512 + lane * 8);

  // ---- inline softmax (exact division); lgkm-only barriers keep vmem loads in flight ----
  {
    float m = vdot;
    #pragma unroll
    for (int off = 32; off; off >>= 1) m = fmaxf(m, __shfl_xor(m, off, 64));
    if (lane == 0) redm[w] = m;
    asm volatile("s_waitcnt lgkmcnt(0)" ::: "memory");
    __builtin_amdgcn_s_barrier();
    float bm = fmaxf(fmaxf(redm[0], redm[1]), fmaxf(redm[2], redm[3]));
    float e = (t < HW) ? expf(vdot - bm) : 0.f;
    float s = e;
    #pragma unroll
    for (int off = 32; off; off >>= 1) s += __shfl_xor(s, off, 64);
    if (lane == 0) reds[w] = s;
    asm volatile("s_waitcnt lgkmcnt(0)" ::: "memory");
    __builtin_amdgcn_s_barrier();
    float bs = reds[0] + reds[1] + reds[2] + reds[3];
    float a = (t < HW) ? (e / bs) : 0.f;
    if (t < HWP) attn_sh[t] = a;
    if ((ob & 3) == 0 && t < HW) {
      int n = nd >> 5, d = nd & 31;
      attn_out[(((size_t)n * 4 + o) * 32 + d) * HW + t] = a;
    }
  }

  // ---- main pipelined loop ----
  #pragma unroll
  for (int kk = 0; kk < 16; ++kk) {
    if (kk == 15) {
      asm volatile("s_waitcnt vmcnt(0) lgkmcnt(0)" ::: "memory");
    } else {
      asm volatile("s_waitcnt vmcnt(6) lgkmcnt(0)" ::: "memory");
    }
    __builtin_amdgcn_s_barrier();
    __builtin_amdgcn_sched_barrier(0);
    __builtin_amdgcn_s_setprio(1);
    const char* bp = ldsb + (kk & 1) * 13312;
    if ((kk & 1) == 0) {
      #pragma unroll
      for (int j = 0; j < 13; ++j) {
        half8 bh = *(const half8*)(bp + j * 1024 + lane * 16);
        acc[0][j] = MFMAH(Ah0[0], bh, acc[0][j]);
        acc[1][j] = MFMAH(Ah0[1], bh, acc[1][j]);
      }
    } else {
      #pragma unroll
      for (int j = 0; j < 13; ++j) {
        half8 bh = *(const half8*)(bp + j * 1024 + lane * 16);
        acc[0][j] = MFMAH(Ah1[0], bh, acc[0][j]);
        acc[1][j] = MFMAH(Ah1[1], bh, acc[1][j]);
      }
    }
    __builtin_amdgcn_s_setprio(0);
    __builtin_amdgcn_sched_barrier(0);
    asm volatile("s_waitcnt lgkmcnt(0)" ::: "memory");
    __builtin_amdgcn_s_barrier();
    if (kk < 14) {
      stage(ldsb + (kk & 1) * 13312, kk + 2);          // 4 vmem
      if ((kk & 1) == 0) {                             // A(kk+2) hi -> slot0: 2 vmem
        #pragma unroll
        for (int f = 0; f < 2; ++f)
          Ah0[f] = *(const half8*)(WvA + ((size_t)((kk + 2) * 2 + 0) * 128 + rbase + f) * 512 + lane * 8);
      } else {                                         // A(kk+2) hi -> slot1
        #pragma unroll
        for (int f = 0; f < 2; ++f)
          Ah1[f] = *(const half8*)(WvA + ((size_t)((kk + 2) * 2 + 0) * 128 + rbase + f) * 512 + lane * 8);
      }
    }
  }

  // epilogue: per-wave direct S1/S2/S3 (no cross-wave reduction needed).
  // C/D layout: hw-col = lane&15, oc-row-in-frag = (lane>>4)*4 + r.
  float attw[13];
  #pragma unroll
  for (int j = 0; j < 13; ++j) attw[j] = attn_sh[j * 16 + (lane & 15)];
  #pragma unroll
  for (int f = 0; f < 2; ++f) {
    #pragma unroll
    for (int r = 0; r < 4; ++r) {
      float u = 0.f, vsq = 0.f, wsum = 0.f;
      #pragma unroll
      for (int j = 0; j < 13; ++j) {
        float v = acc[f][j][r];
        u += v;
        vsq = fmaf(v, v, vsq);
        wsum = fmaf(v, attw[j], wsum);
      }
      #pragma unroll
      for (int off = 8; off; off >>= 1) {
        u += __shfl_xor(u, off, 16);
        vsq += __shfl_xor(vsq, off, 16);
        wsum += __shfl_xor(wsum, off, 16);
      }
      if ((lane & 15) == 0) {
        int oc = (rbase + f) * 16 + (lane >> 4) * 4 + r;
        size_t base = (size_t)nd * OC + oc;
        S1[base] = u;
        S2[base] = vsq;
        S3[base] = wsum;
      }
    }
  }
}

// ---------------- head: per (nd,oc) InstanceNorm + gelu + Wout reduce ----------------
__global__ void head_final(const float* __restrict__ S1, const float* __restrict__ S2,
                           const float* __restrict__ S3,
                           const float* __restrict__ gamma, const float* __restrict__ beta,
                           const float* __restrict__ Wout, const float* __restrict__ bout,
                           float* __restrict__ outs) {
  int nd = blockIdx.x;
  int t = threadIdx.x;
  int w = t >> 6, lane = t & 63;
  __shared__ float redp[16];
  float po[4] = {0.f, 0.f, 0.f, 0.f};
  #pragma unroll
  for (int i = 0; i < 8; ++i) {
    int oc = i * 256 + t;
    float m1 = S1[(size_t)nd * OC + oc] * INV196;
    float m2 = S2[(size_t)nd * OC + oc] * INV196;
    float var = m2 - m1 * m1;
    float rs = rsqrtf(var + 1e-5f);
    float xh = (S3[(size_t)nd * OC + oc] - m1) * rs * gamma[oc] + beta[oc];
    float ge = 0.5f * xh * (1.0f + erff(xh * 0.70710678118654752f));
    po[i >> 1] = fmaf(ge, Wout[oc], po[i >> 1]);
  }
  #pragma unroll
  for (int off = 32; off; off >>= 1) {
    #pragma unroll
    for (int o = 0; o < 4; ++o) po[o] += __shfl_down(po[o], off, 64);
  }
  if (lane == 0) {
    #pragma unroll
    for (int o = 0; o < 4; ++o) redp[w * 4 + o] = po[o];
  }
  __syncthreads();
  if (t < 4) {
    int o = t;
    float s = redp[o] + redp[4 + o] + redp[8 + o] + redp[12 + o] + bout[o];
    int n = nd >> 5, d = nd & 31;
    outs[o * 64 + n * 32 + d] = s;
  }
}

}  // namespace

extern "C" void kernel_launch(void* const* d_in, const int* in_sizes, int n_in,
                              void* d_out, int out_size, void* d_ws, size_t ws_size,
                              hipStream_t stream) {
  const float* x     = (const float*)d_in[0];
  const float* Wq    = (const float*)d_in[1];
  const float* Wk    = (const float*)d_in[2];
  const float* Wv    = (const float*)d_in[3];
  const float* gamma = (const float*)d_in[4];
  const float* beta  = (const float*)d_in[5];
  const float* Wout  = (const float*)d_in[6];
  const float* bout  = (const float*)d_in[7];
  float* out      = (float*)d_out;
  float* attn_out = out;            // (N,4,D,196) = 50176 floats
  float* outs     = out + 50176;    // (4,N,1,D)   = 256 floats

  float* ws = (float*)d_ws;
  _Float16*  WvA  = (_Float16*)ws;                      // 2097152 f16 -> [0, 1048576) floats
  _Float16*  xpH  = (_Float16*)(ws + 1048576);          // 7340032 f16 -> 3670016 floats
  float*     xm   = ws + 4718592;                       // 32768
  float*     dotb = ws + 4751360;                       // 57344
  float*     S1   = ws + 4808704;                       // 131072
  float*     S2   = ws + 4939776;                       // 131072
  float*     S3   = ws + 5070848;                       // 131072

  fat_prep<<<4608, 256, 0, stream>>>(x, Wv, WvA, xpH, xm);
  attn_dots<<<256, 256, 0, stream>>>(Wq, Wk, xm, xpH, dotb);
  moments_mfma<<<1024, 256, 0, stream>>>(WvA, xpH, dotb, attn_out, S1, S2, S3);
  head_final<<<64, 256, 0, stream>>>(S1, S2, S3, gamma, beta, Wout, bout, outs);
}

// Round 20
// 70.301 us; speedup vs baseline: 2.0107x; 1.0239x over previous
//
#include <hip/hip_runtime.h>
#include <math.h>

namespace {

constexpr int HW  = 196;
constexpr int HWP = 224;
constexpr int OC  = 2048;
constexpr float TEMP   = 0.35355339059327373f;  // 1/sqrt(KEY_DIM)
constexpr float INV196 = 1.0f / 196.0f;

typedef __attribute__((ext_vector_type(8))) _Float16 half8;
typedef __attribute__((ext_vector_type(4))) float f32x4;

__device__ __forceinline__ void gload_lds16(const void* g, void* l) {
  __builtin_amdgcn_global_load_lds(
      (const __attribute__((address_space(1))) void*)g,
      (__attribute__((address_space(3))) void*)l, 16, 0, 0);
}

#define MFMAH(a, b, c) __builtin_amdgcn_mfma_f32_16x16x32_f16((a), (b), (c), 0, 0, 0)
#define SBAR0() __builtin_amdgcn_sched_barrier(0)

// ================= K1: WvA prep (512 blocks) || pool (4096 blocks, XCD-affine) =================
__global__ __launch_bounds__(256) void fat_prep(
    const float* __restrict__ x, const float* __restrict__ Wv,
    _Float16* __restrict__ WvA,
    _Float16* __restrict__ xpH, float* __restrict__ xm) {
  __shared__ float tl[8][264];
  int bid = blockIdx.x;
  int t = threadIdx.x;
  if (bid < 512) {
    int kk = bid >> 5;
    int rq = bid & 31;
    int w = t >> 6, lane = t & 63;
    int r = rq * 4 + w;
    int oc = r * 16 + (lane & 15);
    int c0 = kk * 32 + (lane >> 4) * 8;
    const float* src = Wv + (size_t)oc * 512 + c0;
    float4 v0 = *(const float4*)src;
    float4 v1 = *(const float4*)(src + 4);
    float vals[8] = {v0.x, v0.y, v0.z, v0.w, v1.x, v1.y, v1.z, v1.w};
    half8 hi, lo;
    #pragma unroll
    for (int e = 0; e < 8; ++e) {
      _Float16 h = (_Float16)vals[e];
      hi[e] = h;
      lo[e] = (_Float16)(vals[e] - (float)h);
    }
    *(half8*)(WvA + ((size_t)(kk * 2 + 0) * 128 + r) * 512 + lane * 8) = hi;
    *(half8*)(WvA + ((size_t)(kk * 2 + 1) * 128 + r) * 512 + lane * 8) = lo;
  } else {
    int pb = bid - 512;
    int nd = (((pb >> 9) & 7) << 3) | (pb & 7);   // XCD-affine
    int cg = (pb >> 3) & 63;
    int n = nd >> 5, d = nd & 31;
    int c0 = cg * 8;
    int cl = t >> 5, s = t & 31;
    const float* xr = x + (((size_t)(n * 512 + c0 + cl)) * 32 + d) * 256;
    float4 va = *(const float4*)(xr + s * 8);
    float4 vb = *(const float4*)(xr + s * 8 + 4);
    *(float4*)&tl[cl][s * 8] = va;
    *(float4*)&tl[cl][s * 8 + 4] = vb;
    float rs = va.x + va.y + va.z + va.w + vb.x + vb.y + vb.z + vb.w;
    #pragma unroll
    for (int off = 16; off; off >>= 1) rs += __shfl_xor(rs, off, 32);
    if (s == 0) xm[nd * 512 + c0 + cl] = rs * (1.0f / 256.0f);
    __syncthreads();
    if (t < HWP) {
      int hw = t;
      half8 hi;
      if (hw < HW) {
        int y = hw / 14, xx = hw - y * 14;
        #pragma unroll
        for (int c = 0; c < 8; ++c) {
          const float* q = &tl[c][y * 16 + xx];
          float val = (q[0] + q[1] + q[2] + q[16] + q[17] + q[18] +
                       q[32] + q[33] + q[34]) * (1.0f / 9.0f);
          hi[c] = (_Float16)val;
        }
      } else {
        #pragma unroll
        for (int c = 0; c < 8; ++c) hi[c] = (_Float16)0.f;
      }
      *(half8*)(xpH + ((size_t)nd * HWP + hw) * 512 + c0) = hi;
    }
  }
}

// ---------------- attn dots: dot[nd][o][hw] = qw[o] . xp_hi[hw]  (4 lanes per hw) ----------------
__global__ __launch_bounds__(256) void attn_dots(
    const float* __restrict__ Wq, const float* __restrict__ Wk,
    const float* __restrict__ xm,
    const _Float16* __restrict__ xpH, float* __restrict__ dotb) {
  int b = blockIdx.x;
  int nd = b >> 2, ch = b & 3;
  int t = threadIdx.x;
  __shared__ float xs[512];
  __shared__ float qsA[32];
  __shared__ float qw[2048];
  xs[t] = xm[nd * 512 + t];
  xs[t + 256] = xm[nd * 512 + t + 256];
  __syncthreads();
  {
    int k = t >> 3, j = t & 7;
    float p = 0.f;
    #pragma unroll 8
    for (int c = j; c < 512; c += 8) p = fmaf(Wq[k * 512 + c], xs[c], p);
    p += __shfl_xor(p, 4, 8);
    p += __shfl_xor(p, 2, 8);
    p += __shfl_xor(p, 1, 8);
    if (j == 0) qsA[k] = p;
  }
  __syncthreads();
  {
    int o = t >> 6;
    int c0 = (t & 63) * 8;
    float q[8];
    #pragma unroll
    for (int kd = 0; kd < 8; ++kd) q[kd] = qsA[o * 8 + kd];
    #pragma unroll
    for (int e = 0; e < 8; ++e) {
      float a = 0.f;
      #pragma unroll
      for (int kd = 0; kd < 8; ++kd)
        a = fmaf(q[kd], Wk[(size_t)(o * 8 + kd) * 512 + c0 + e], a);
      qw[o * 512 + c0 + e] = a;
    }
  }
  __syncthreads();
  if (t < 224) {
    int hwl = t >> 2, q = t & 3;
    int hw = ch * 56 + hwl;
    const _Float16* rh = xpH + ((size_t)nd * HWP + hw) * 512;
    float d0 = 0.f, d1 = 0.f, d2 = 0.f, d3 = 0.f;
    #pragma unroll
    for (int k = 0; k < 16; ++k) {
      int cb = q * 8 + k * 32;           // interleaved c-blocks: conflict-free qw banks
      half8 h = *(const half8*)(rh + cb);
      #pragma unroll
      for (int e = 0; e < 8; ++e) {
        float xv = (float)h[e];
        d0 = fmaf(qw[cb + e], xv, d0);
        d1 = fmaf(qw[512 + cb + e], xv, d1);
        d2 = fmaf(qw[1024 + cb + e], xv, d2);
        d3 = fmaf(qw[1536 + cb + e], xv, d3);
      }
    }
    d0 += __shfl_xor(d0, 1, 4); d0 += __shfl_xor(d0, 2, 4);
    d1 += __shfl_xor(d1, 1, 4); d1 += __shfl_xor(d1, 2, 4);
    d2 += __shfl_xor(d2, 1, 4); d2 += __shfl_xor(d2, 2, 4);
    d3 += __shfl_xor(d3, 1, 4); d3 += __shfl_xor(d3, 2, 4);
    float r = (q == 0) ? d0 : (q == 1) ? d1 : (q == 2) ? d2 : d3;
    dotb[((size_t)nd * 4 + q) * HWP + hw] = r * TEMP;
  }
}

// ---------------- moments + inline softmax + attention-weighted sum (1-product f16 MFMA) ----------
// SINGLE-BARRIER pipeline via 3-way LDS buffer rotation (validated r17 loop minus barrier-B):
// region kk stages buf((kk+2)%3), which was read at iteration kk-1. Every wave executes
// lgkmcnt(0) before arriving at barrier-A(kk), so its kk-1 ds_reads are complete; the barrier
// then makes all reads globally done before any wave stages that buffer -> WAR-safe, no 2nd barrier.
// vmcnt ledger unchanged from r17: ops issued after stage(kk)'s last op = A(kk) 2 + s(kk+1) 4 +
// A(kk+1) 2 = 8 >= 6 -> steady vmcnt(6); kk=15 -> vmcnt(0). A-loads are register loads (compiler
// auto-waits their uses).
__global__ __launch_bounds__(256, 2) void moments_mfma(
    const _Float16* __restrict__ WvA, const _Float16* __restrict__ xpH,
    const float* __restrict__ dotb, float* __restrict__ attn_out,
    float* __restrict__ S1, float* __restrict__ S2, float* __restrict__ S3) {
  int bid = blockIdx.x;
  int ob = (bid >> 3) & 15;
  int nd = ((bid >> 7) << 3) | (bid & 7);
  int o = ob >> 2;
  int t = threadIdx.x;
  int w = t >> 6, lane = t & 63;
  int rbase = ob * 8 + w * 2;            // this wave's 2 oc-rows
  __shared__ char ldsb[39936];           // 3 x 13312 B buffers: [j(13)][granule(64)][16B]
  __shared__ float attn_sh[HWP];
  __shared__ float redm[4];
  __shared__ float reds[4];
  const _Float16* xph = xpH + (size_t)nd * HWP * 512;

  float vdot = (t < HW) ? dotb[((size_t)nd * 4 + o) * HWP + t] : -3.0e38f;

  f32x4 acc[2][13];
  #pragma unroll
  for (int f = 0; f < 2; ++f)
    #pragma unroll
    for (int j = 0; j < 13; ++j) acc[f][j] = (f32x4){0.f, 0.f, 0.f, 0.f};

  // stage one 13312B kk-tile: every wave issues exactly 4 gload_lds instructions
  auto stage = [&](char* buf, int kk) {
    #pragma unroll
    for (int i = 0; i < 3; ++i) {
      int G = i * 256 + t;
      int j = G >> 6, g = G & 63;
      int hwl = g & 15, bb = g >> 4;
      const _Float16* src = xph + (size_t)(j * 16 + hwl) * 512 + kk * 32 + bb * 8;
      gload_lds16((const void*)src, (void*)(buf + G * 16));
    }
    if (lane < 16) {
      int G = 768 + w * 16 + lane;
      int g = G & 63;
      int hwl = g & 15, bb = g >> 4;
      const _Float16* src = xph + (size_t)(12 * 16 + hwl) * 512 + kk * 32 + bb * 8;
      gload_lds16((const void*)src, (void*)(buf + G * 16));
    }
  };

  stage(ldsb, 0);                        // s(0) -> buf0: 4 vmem/wave
  SBAR0();
  stage(ldsb + 13312, 1);                // s(1) -> buf1: 4
  SBAR0();
  half8 Ah0[2], Ah1[2];
  #pragma unroll
  for (int f = 0; f < 2; ++f)            // A(0) hi -> slot0: 2 vmem
    Ah0[f] = *(const half8*)(WvA + ((size_t)(0 * 2 + 0) * 128 + rbase + f) * 512 + lane * 8);
  #pragma unroll
  for (int f = 0; f < 2; ++f)            // A(1) hi -> slot1: 2 vmem
    Ah1[f] = *(const half8*)(WvA + ((size_t)(1 * 2 + 0) * 128 + rbase + f) * 512 + lane * 8);
  SBAR0();

  // ---- inline softmax (exact division); lgkm-only barriers keep vmem loads in flight ----
  {
    float m = vdot;
    #pragma unroll
    for (int off = 32; off; off >>= 1) m = fmaxf(m, __shfl_xor(m, off, 64));
    if (lane == 0) redm[w] = m;
    asm volatile("s_waitcnt lgkmcnt(0)" ::: "memory");
    __builtin_amdgcn_s_barrier();
    float bm = fmaxf(fmaxf(redm[0], redm[1]), fmaxf(redm[2], redm[3]));
    float e = (t < HW) ? expf(vdot - bm) : 0.f;
    float s = e;
    #pragma unroll
    for (int off = 32; off; off >>= 1) s += __shfl_xor(s, off, 64);
    if (lane == 0) reds[w] = s;
    asm volatile("s_waitcnt lgkmcnt(0)" ::: "memory");
    __builtin_amdgcn_s_barrier();
    float bs = reds[0] + reds[1] + reds[2] + reds[3];
    float a = (t < HW) ? (e / bs) : 0.f;
    if (t < HWP) attn_sh[t] = a;
    if ((ob & 3) == 0 && t < HW) {
      int n = nd >> 5, d = nd & 31;
      attn_out[(((size_t)n * 4 + o) * 32 + d) * HW + t] = a;
    }
  }

  // ---- main pipelined loop: ONE barrier per iteration ----
  #pragma unroll
  for (int kk = 0; kk < 16; ++kk) {
    if (kk == 15) {
      asm volatile("s_waitcnt vmcnt(0) lgkmcnt(0)" ::: "memory");
    } else {
      asm volatile("s_waitcnt vmcnt(6) lgkmcnt(0)" ::: "memory");
    }
    __builtin_amdgcn_s_barrier();
    SBAR0();
    __builtin_amdgcn_s_setprio(1);
    const char* bp = ldsb + (kk % 3) * 13312;
    if ((kk & 1) == 0) {
      #pragma unroll
      for (int j = 0; j < 13; ++j) {
        half8 bh = *(const half8*)(bp + j * 1024 + lane * 16);
        acc[0][j] = MFMAH(Ah0[0], bh, acc[0][j]);
        acc[1][j] = MFMAH(Ah0[1], bh, acc[1][j]);
      }
    } else {
      #pragma unroll
      for (int j = 0; j < 13; ++j) {
        half8 bh = *(const half8*)(bp + j * 1024 + lane * 16);
        acc[0][j] = MFMAH(Ah1[0], bh, acc[0][j]);
        acc[1][j] = MFMAH(Ah1[1], bh, acc[1][j]);
      }
    }
    __builtin_amdgcn_s_setprio(0);
    SBAR0();
    if (kk < 14) {
      stage(ldsb + ((kk + 2) % 3) * 13312, kk + 2);    // 4 vmem; buffer last read at kk-1
      SBAR0();
      if ((kk & 1) == 0) {                             // A(kk+2) hi -> slot0: 2 vmem
        #pragma unroll
        for (int f = 0; f < 2; ++f)
          Ah0[f] = *(const half8*)(WvA + ((size_t)((kk + 2) * 2 + 0) * 128 + rbase + f) * 512 + lane * 8);
      } else {                                         // A(kk+2) hi -> slot1
        #pragma unroll
        for (int f = 0; f < 2; ++f)
          Ah1[f] = *(const half8*)(WvA + ((size_t)((kk + 2) * 2 + 0) * 128 + rbase + f) * 512 + lane * 8);
      }
      SBAR0();
    }
  }

  // epilogue: per-wave direct S1/S2/S3 (no cross-wave reduction needed).
  // C/D layout: hw-col = lane&15, oc-row-in-frag = (lane>>4)*4 + r.
  float attw[13];
  #pragma unroll
  for (int j = 0; j < 13; ++j) attw[j] = attn_sh[j * 16 + (lane & 15)];
  #pragma unroll
  for (int f = 0; f < 2; ++f) {
    #pragma unroll
    for (int r = 0; r < 4; ++r) {
      float u = 0.f, vsq = 0.f, wsum = 0.f;
      #pragma unroll
      for (int j = 0; j < 13; ++j) {
        float v = acc[f][j][r];
        u += v;
        vsq = fmaf(v, v, vsq);
        wsum = fmaf(v, attw[j], wsum);
      }
      #pragma unroll
      for (int off = 8; off; off >>= 1) {
        u += __shfl_xor(u, off, 16);
        vsq += __shfl_xor(vsq, off, 16);
        wsum += __shfl_xor(wsum, off, 16);
      }
      if ((lane & 15) == 0) {
        int oc = (rbase + f) * 16 + (lane >> 4) * 4 + r;
        size_t base = (size_t)nd * OC + oc;
        S1[base] = u;
        S2[base] = vsq;
        S3[base] = wsum;
      }
    }
  }
}

// ---------------- head: per (nd,oc) InstanceNorm + gelu + Wout reduce ----------------
__global__ void head_final(const float* __restrict__ S1, const float* __restrict__ S2,
                           const float* __restrict__ S3,
                           const float* __restrict__ gamma, const float* __restrict__ beta,
                           const float* __restrict__ Wout, const float* __restrict__ bout,
                           float* __restrict__ outs) {
  int nd = blockIdx.x;
  int t = threadIdx.x;
  int w = t >> 6, lane = t & 63;
  __shared__ float redp[16];
  float po[4] = {0.f, 0.f, 0.f, 0.f};
  #pragma unroll
  for (int i = 0; i < 8; ++i) {
    int oc = i * 256 + t;
    float m1 = S1[(size_t)nd * OC + oc] * INV196;
    float m2 = S2[(size_t)nd * OC + oc] * INV196;
    float var = m2 - m1 * m1;
    float rs = rsqrtf(var + 1e-5f);
    float xh = (S3[(size_t)nd * OC + oc] - m1) * rs * gamma[oc] + beta[oc];
    float ge = 0.5f * xh * (1.0f + erff(xh * 0.70710678118654752f));
    po[i >> 1] = fmaf(ge, Wout[oc], po[i >> 1]);
  }
  #pragma unroll
  for (int off = 32; off; off >>= 1) {
    #pragma unroll
    for (int o = 0; o < 4; ++o) po[o] += __shfl_down(po[o], off, 64);
  }
  if (lane == 0) {
    #pragma unroll
    for (int o = 0; o < 4; ++o) redp[w * 4 + o] = po[o];
  }
  __syncthreads();
  if (t < 4) {
    int o = t;
    float s = redp[o] + redp[4 + o] + redp[8 + o] + redp[12 + o] + bout[o];
    int n = nd >> 5, d = nd & 31;
    outs[o * 64 + n * 32 + d] = s;
  }
}

}  // namespace

extern "C" void kernel_launch(void* const* d_in, const int* in_sizes, int n_in,
                              void* d_out, int out_size, void* d_ws, size_t ws_size,
                              hipStream_t stream) {
  const float* x     = (const float*)d_in[0];
  const float* Wq    = (const float*)d_in[1];
  const float* Wk    = (const float*)d_in[2];
  const float* Wv    = (const float*)d_in[3];
  const float* gamma = (const float*)d_in[4];
  const float* beta  = (const float*)d_in[5];
  const float* Wout  = (const float*)d_in[6];
  const float* bout  = (const float*)d_in[7];
  float* out      = (float*)d_out;
  float* attn_out = out;            // (N,4,D,196) = 50176 floats
  float* outs     = out + 50176;    // (4,N,1,D)   = 256 floats

  float* ws = (float*)d_ws;
  _Float16*  WvA  = (_Float16*)ws;                      // 2097152 f16 -> [0, 1048576) floats
  _Float16*  xpH  = (_Float16*)(ws + 1048576);          // 7340032 f16 -> 3670016 floats
  float*     xm   = ws + 4718592;                       // 32768
  float*     dotb = ws + 4751360;                       // 57344
  float*     S1   = ws + 4808704;                       // 131072
  float*     S2   = ws + 4939776;                       // 131072
  float*     S3   = ws + 5070848;                       // 131072

  fat_prep<<<4608, 256, 0, stream>>>(x, Wv, WvA, xpH, xm);
  attn_dots<<<256, 256, 0, stream>>>(Wq, Wk, xm, xpH, dotb);
  moments_mfma<<<1024, 256, 0, stream>>>(WvA, xpH, dotb, attn_out, S1, S2, S3);
  head_final<<<64, 256, 0, stream>>>(S1, S2, S3, gamma, beta, Wout, bout, outs);
}